// Round 4
// baseline (485.314 us; speedup 1.0000x reference)
//
#include <hip/hip_runtime.h>
#include <hip/hip_bf16.h>

typedef __attribute__((ext_vector_type(8))) short short8;
typedef __attribute__((ext_vector_type(4))) short short4v;
typedef __attribute__((ext_vector_type(4))) float f32x4;
typedef __attribute__((ext_vector_type(16))) float f32x16;

#define S_DIM 384
#define N_DIM 512
#define C_DIM 32
#define CZ_DIM 128
#define MROWS (S_DIM * C_DIM) /* 12288 */

__device__ __forceinline__ void async16(const void* g, void* l) {
  __builtin_amdgcn_global_load_lds(
      (const __attribute__((address_space(1))) void*)g,
      (__attribute__((address_space(3))) void*)l, 16, 0, 0);
}

__device__ __forceinline__ short bf16b(float x) {
  __hip_bfloat16 h = __float2bfloat16(x);
  return *reinterpret_cast<short*>(&h);
}

// Kernel 0: w_final fp32 -> bf16 K-permuted (Wfp[z][d*32+c]) + w_ab transpose
// (w_abT[c*64+dd] = w_ab[dd*32+c], uniform-row layout for prep's s_loads).
__global__ __launch_bounds__(256) void conv_wf(const float* __restrict__ w_final,
                                               const float* __restrict__ w_ab,
                                               __hip_bfloat16* __restrict__ Wfp,
                                               float* __restrict__ w_abT) {
  const int i = blockIdx.x * 256 + threadIdx.x;
  if (i < 2048) {
    const int c = i >> 6, dd = i & 63;
    w_abT[i] = w_ab[dd * C_DIM + c];
  }
  const int z = i >> 10, kp = i & 1023;
  const int d = kp >> 5, c2 = kp & 31;
  Wfp[i] = __float2bfloat16(w_final[(size_t)z * 1024 + c2 * 32 + d]);
}

// Kernel 1: LayerNorm + w_ab projection (GEMV with register accumulators;
// weights via wave-uniform s_load batches from w_abT).
__global__ __launch_bounds__(256) void prep_kernel(
    const float* __restrict__ m_si, const float* __restrict__ ln_g,
    const float* __restrict__ ln_b, const float* __restrict__ w_abT,
    __hip_bfloat16* __restrict__ Abt, __hip_bfloat16* __restrict__ Bbt) {
  const int n = blockIdx.x * 256 + threadIdx.x;  // 0..511
  const int s = blockIdx.y;                      // 0..383
  const float* x = m_si + ((size_t)s * N_DIM + n) * C_DIM;

  float mn[C_DIM];
#pragma unroll
  for (int i = 0; i < 8; ++i) {
    float4 t = ((const float4*)x)[i];
    mn[4 * i + 0] = t.x; mn[4 * i + 1] = t.y;
    mn[4 * i + 2] = t.z; mn[4 * i + 3] = t.w;
  }
  float sum = 0.f;
#pragma unroll
  for (int c = 0; c < C_DIM; ++c) sum += mn[c];
  const float mu = sum * (1.f / 32.f);
  float sq = 0.f;
#pragma unroll
  for (int c = 0; c < C_DIM; ++c) { float d = mn[c] - mu; sq += d * d; }
  const float rstd = rsqrtf(sq * (1.f / 32.f) + 1e-5f);
#pragma unroll
  for (int c = 0; c < C_DIM; ++c)
    mn[c] = (mn[c] - mu) * rstd * ln_g[c] + ln_b[c];

  float acc[64];
#pragma unroll
  for (int dd = 0; dd < 64; ++dd) acc[dd] = 0.f;
#pragma unroll
  for (int c = 0; c < C_DIM; ++c) {
    const float* wrow = w_abT + c * 64;  // uniform address -> s_load_dwordx16
#pragma unroll
    for (int dd = 0; dd < 64; ++dd) acc[dd] += mn[c] * wrow[dd];
  }
#pragma unroll
  for (int d = 0; d < 32; ++d) {
    Abt[((size_t)(s * 32 + d)) * N_DIM + n] = __float2bfloat16(acc[d] * (1.f / 512.f));
    Bbt[((size_t)(s * 32 + d)) * N_DIM + n] = __float2bfloat16(acc[d + 32]);
  }
}

// Kernel 2: fused outer-product GEMM (128x128 tile, K=512, BK=64, 32x32x16
// MFMA, 2x2 tiles/wave) + w_final projection epilogue.
__global__ __launch_bounds__(256, 4) void fused_opm(
    const __hip_bfloat16* __restrict__ Abt, const __hip_bfloat16* __restrict__ Bbt,
    const __hip_bfloat16* __restrict__ Wfp, const float* __restrict__ b_final,
    float* __restrict__ out) {
  // As [128][64] (16 KB) + Bs [128][64] (16 KB); Oc [16][1024] (32 KB) aliases
  // them post-main-loop. 16-B k-groups XOR-swizzled by row (kg ^= row&7).
  __shared__ __align__(16) char smem[32768];
  __hip_bfloat16* As = (__hip_bfloat16*)smem;
  __hip_bfloat16* Bs = (__hip_bfloat16*)(smem + 16384);

  const int tid = threadIdx.x;
  const int wave = tid >> 6;
  const int lane = tid & 63;
  const int fr = lane & 15;   // 16x16 MFMA row index (epilogue)
  const int fq = lane >> 4;   // 16x16 MFMA quad (epilogue)
  const int r31 = lane & 31;  // 32x32 MFMA row index (main)
  const int khi = lane >> 5;  // 32x32 MFMA k-half (main)
  const int wr = wave >> 1, wc = wave & 1;
  const int bi = blockIdx.y, bj = blockIdx.x;

  const size_t m0 = (size_t)bi * 128;
  const size_t n0 = (size_t)bj * 128;

  // Staging: slot (row = tid>>3 [+32/issue], phys kg = tid&7) holds logical
  // kg = (tid&7) ^ (row&7) -- swizzle realized on the GLOBAL fetch address.
  const int srow = tid >> 3;
  const int skg = (tid & 7) ^ (srow & 7);
  const __hip_bfloat16* gA = Abt + (m0 + srow) * N_DIM + skg * 8;
  const __hip_bfloat16* gB = Bbt + (n0 + srow) * N_DIM + skg * 8;
  char* ldsA = smem + tid * 16;
  char* ldsB = smem + 16384 + tid * 16;

  f32x16 acc[2][2];
#pragma unroll
  for (int i = 0; i < 2; ++i)
#pragma unroll
    for (int j = 0; j < 2; ++j)
#pragma unroll
      for (int r = 0; r < 16; ++r) acc[i][j][r] = 0.f;

  for (int kt = 0; kt < 8; ++kt) {
    const int k0 = kt * 64;
    __syncthreads();
#pragma unroll
    for (int i = 0; i < 4; ++i) {
      async16(gA + (size_t)(i * 32) * N_DIM + k0, ldsA + i * 4096);
      async16(gB + (size_t)(i * 32) * N_DIM + k0, ldsB + i * 4096);
    }
    __syncthreads();

#pragma unroll
    for (int s = 0; s < 4; ++s) {
      short8 af[2], bfv[2];
#pragma unroll
      for (int mt = 0; mt < 2; ++mt) {
        const int row = wr * 64 + mt * 32 + r31;
        const int kp = (s * 2 + khi) ^ (row & 7);
        af[mt] = *(const short8*)(As + row * 64 + kp * 8);
      }
#pragma unroll
      for (int nt = 0; nt < 2; ++nt) {
        const int row = wc * 64 + nt * 32 + r31;
        const int kp = (s * 2 + khi) ^ (row & 7);
        bfv[nt] = *(const short8*)(Bs + row * 64 + kp * 8);
      }
#pragma unroll
      for (int mt = 0; mt < 2; ++mt)
#pragma unroll
        for (int nt = 0; nt < 2; ++nt)
          acc[mt][nt] = __builtin_amdgcn_mfma_f32_32x32x16_bf16(
              af[mt], bfv[nt], acc[mt][nt], 0, 0, 0);
    }
  }

  // ---- Epilogue phase 1: acc -> Oc bf16, k' = d*32+c (matches Wfp).
  // 32x32 C/D map: col=lane&31, row c=(reg&3)+8*(reg>>2)+4*(lane>>5) -> per
  // (q=reg>>2): 4 consecutive c at fixed d -> one ds_write_b64.
  __syncthreads();
  __hip_bfloat16* Oc = (__hip_bfloat16*)smem;  // [16 cells][1024]
#pragma unroll
  for (int mt = 0; mt < 2; ++mt) {
#pragma unroll
    for (int nt = 0; nt < 2; ++nt) {
      const int cell = (wr * 2 + mt) * 4 + wc * 2 + nt;
      const int d = r31;
#pragma unroll
      for (int q = 0; q < 4; ++q) {
        const int gk = d * 8 + q * 2 + khi;  // 8-B group of k' = d*32 + q*8 + khi*4
        const int gp = gk ^ (((gk >> 4) & 7) << 1) ^ ((cell & 7) << 1);
        short4v pk;
        pk[0] = bf16b(acc[mt][nt][q * 4 + 0]);
        pk[1] = bf16b(acc[mt][nt][q * 4 + 1]);
        pk[2] = bf16b(acc[mt][nt][q * 4 + 2]);
        pk[3] = bf16b(acc[mt][nt][q * 4 + 3]);
        *(short4v*)(Oc + cell * 1024 + gp * 4) = pk;
      }
    }
  }
  __syncthreads();

  // ---- Epilogue phase 2: Z[16][128] = Oc[16][1024] @ Wfp[128][1024]^T ----
  // 2 z-tiles/wave, depth-4 software pipeline (3 loads in flight) to cover
  // the ~250-cyc L2 latency of the Wfp loads.
  const f32x4 fzero = {0.f, 0.f, 0.f, 0.f};
  f32x4 zc[2][2] = {{fzero, fzero}, {fzero, fzero}};
  const int zt0 = wave * 2;
  const __hip_bfloat16* wp0 = Wfp + (size_t)(zt0 * 16 + fr) * 1024 + fq * 8;
  const __hip_bfloat16* wp1 = wp0 + (size_t)16 * 1024;

  short8 oa_buf[4], w0_buf[4], w1_buf[4];
#pragma unroll
  for (int p = 0; p < 3; ++p) {
    const int gk = p * 8 + fq * 2;
    const int gp = gk ^ (((gk >> 4) & 7) << 1) ^ ((fr & 7) << 1);
    oa_buf[p] = *(const short8*)(Oc + fr * 1024 + gp * 4);
    w0_buf[p] = *(const short8*)(wp0 + p * 32);
    w1_buf[p] = *(const short8*)(wp1 + p * 32);
  }
#pragma unroll
  for (int kk = 0; kk < 32; ++kk) {
    const int cur = kk & 3;
    if (kk < 29) {
      const int kn = kk + 3;
      const int nxt = kn & 3;
      const int gk = kn * 8 + fq * 2;
      const int gp = gk ^ (((gk >> 4) & 7) << 1) ^ ((fr & 7) << 1);
      oa_buf[nxt] = *(const short8*)(Oc + fr * 1024 + gp * 4);
      w0_buf[nxt] = *(const short8*)(wp0 + kn * 32);
      w1_buf[nxt] = *(const short8*)(wp1 + kn * 32);
    }
    zc[0][kk & 1] = __builtin_amdgcn_mfma_f32_16x16x32_bf16(oa_buf[cur], w0_buf[cur],
                                                            zc[0][kk & 1], 0, 0, 0);
    zc[1][kk & 1] = __builtin_amdgcn_mfma_f32_16x16x32_bf16(oa_buf[cur], w1_buf[cur],
                                                            zc[1][kk & 1], 0, 0, 0);
  }

  // ---- Epilogue phase 3: z-write (+ b_final) ----
  const int i0 = bi * 4, j0 = bj * 4;
#pragma unroll
  for (int t = 0; t < 2; ++t) {
    const int zcol = (zt0 + t) * 16 + fr;
    const float bz = b_final[zcol];
    const f32x4 za = zc[t][0] + zc[t][1];
#pragma unroll
    for (int r = 0; r < 4; ++r) {
      const int cell = fq * 4 + r;  // 16x16 D row = cell index
      const int li = cell >> 2, lj = cell & 3;
      out[((size_t)(i0 + li) * S_DIM + (j0 + lj)) * CZ_DIM + zcol] = za[r] + bz;
    }
  }
}

extern "C" void kernel_launch(void* const* d_in, const int* in_sizes, int n_in,
                              void* d_out, int out_size, void* d_ws, size_t ws_size,
                              hipStream_t stream) {
  const float* m_si = (const float*)d_in[0];
  const float* ln_g = (const float*)d_in[1];
  const float* ln_b = (const float*)d_in[2];
  const float* w_ab = (const float*)d_in[3];
  const float* w_final = (const float*)d_in[4];
  const float* b_final = (const float*)d_in[5];
  float* out = (float*)d_out;

  char* ws = (char*)d_ws;
  __hip_bfloat16* Abt = (__hip_bfloat16*)ws;                                 // 12.58 MB
  __hip_bfloat16* Bbt = (__hip_bfloat16*)(ws + (size_t)MROWS * N_DIM * 2);   // 12.58 MB
  __hip_bfloat16* Wfp = (__hip_bfloat16*)(ws + (size_t)MROWS * N_DIM * 4);   // 256 KB
  float* w_abT = (float*)(ws + (size_t)MROWS * N_DIM * 4 + CZ_DIM * 1024 * 2);  // 8 KB

  conv_wf<<<dim3((CZ_DIM * 1024) / 256), 256, 0, stream>>>(w_final, w_ab, Wfp, w_abT);
  prep_kernel<<<dim3(2, S_DIM), 256, 0, stream>>>(m_si, ln_g, ln_b, w_abT, Abt, Bbt);
  fused_opm<<<dim3(96, 96), 256, 0, stream>>>(Abt, Bbt, Wfp, b_final, out);
}